// Round 20
// baseline (1199.417 us; speedup 1.0000x reference)
//
#include <hip/hip_runtime.h>

typedef _Float16 half8   __attribute__((ext_vector_type(8)));
typedef _Float16 half2_t __attribute__((ext_vector_type(2)));
typedef float    floatx4 __attribute__((ext_vector_type(4)));
typedef unsigned int uintx4 __attribute__((ext_vector_type(4)));
typedef unsigned int uint32;

__device__ __forceinline__ float sigm(float v) { return 1.0f / (1.0f + __expf(-v)); }
__device__ __forceinline__ float tanh_(float v) { float e = __expf(2.0f * v); return (e - 1.0f) / (e + 1.0f); }

__device__ __forceinline__ int dot4(uint32 a, uint32 b, int c) {
#if __has_builtin(__builtin_amdgcn_sdot4)
  return __builtin_amdgcn_sdot4((int)a, (int)b, c, false);
#else
  int r = c;
  r += (int)(char)(a)       * (int)(char)(b);
  r += (int)(char)(a >> 8)  * (int)(char)(b >> 8);
  r += (int)(char)(a >> 16) * (int)(char)(b >> 16);
  r += (int)(char)(a >> 24) * (int)(char)(b >> 24);
  return r;
#endif
}

__device__ __forceinline__ uint32 pack_rte(float a, float b) {
  half2_t h; h[0] = (_Float16)a; h[1] = (_Float16)b;
  return __builtin_bit_cast(uint32, h);
}

// ---------------- pack W_ih: f32 -> f16 pairs, flat ----------------
__global__ __launch_bounds__(256) void pack_wih(const float* __restrict__ wih, uint32* __restrict__ wihd) {
  int p = blockIdx.x * 256 + threadIdx.x;   // 1048576 pairs
  wihd[p] = pack_rte(wih[2 * p], wih[2 * p + 1]);
}

// ---------------- pack W_hh: f32 -> i8, layout [k][qt][qi][row], scale 2032 ----------------
__global__ __launch_bounds__(256) void pack_whh8(const float* __restrict__ whh, uintx4* __restrict__ wq8) {
  int p = blockIdx.x * 256 + threadIdx.x;   // 65536 quads
  int row = p & 1023, qi = (p >> 10) & 3, qt = (p >> 12) & 3, kk = p >> 14;
  const float* src = whh + ((size_t)(kk * 1024 + row)) * 256 + qt * 64 + qi * 16;
  uint32 dw[4];
#pragma unroll
  for (int d = 0; d < 4; ++d) {
    uint32 v = 0;
#pragma unroll
    for (int e = 0; e < 4; ++e) {
      int q = (int)rintf(src[d * 4 + e] * 2032.0f);
      q = q > 127 ? 127 : (q < -127 ? -127 : q);
      v |= ((uint32)(q & 0xff)) << (8 * e);
    }
    dw[d] = v;
  }
  wq8[p] = (uintx4){dw[0], dw[1], dw[2], dw[3]};
}

// ---------------- pack ALL x slices: xs[chunk][k][R=b*32+ct][512] f16 ----------------
__global__ __launch_bounds__(256) void pack_x_all(const float* __restrict__ x, uint32* __restrict__ xsd) {
  for (long p = (long)blockIdx.x * 256 + threadIdx.x; p < 33554432L; p += 2097152L) {
    int chunk = (int)(p >> 21);
    int r = (int)(p & 2097151);
    int k  = r >> 19;
    int R  = (r >> 8) & 2047;   // R = b*32 + ct
    int pc = r & 255;
    int b = R >> 5, ct = R & 31;
    int t = chunk * 32 + ct;
    int sk = (k * 1024) / 6;    // 0,170,341,512
    const float* src = x + ((size_t)t * 64 + b) * 1024 + sk + pc * 2;
    xsd[p] = pack_rte(src[0], src[1]);
  }
}

// ---------------- phase 1 (ALL chunks): xg16 = xs @ Wih^T + bias via f16 MFMA ----------------
__global__ __launch_bounds__(256) void gemm_all(const _Float16* __restrict__ xs,
                                                const _Float16* __restrict__ wih16,
                                                const float* __restrict__ bih,
                                                const float* __restrict__ bhh,
                                                _Float16* __restrict__ xg) {
  __shared__ _Float16 SL[18432];
  const int tid = threadIdx.x;
  const int bid = blockIdx.x;
  const int chunk = bid >> 9;
  const int b9 = bid & 511;
  const int nt = b9 & 7, mt = (b9 >> 3) & 15, kb = b9 >> 7;
  const int l = tid & 63;
  const int wid = tid >> 6;
  const int wm = wid >> 1, wn = wid & 1;
  const int lr = l & 15, lk = l >> 4;

  floatx4 acc[4][4] = {};
  const _Float16* xsk = xs + ((size_t)(chunk * 4 + kb) << 20);
  const _Float16* wk  = wih16 + ((size_t)kb << 19);

  for (int kt = 0; kt < 8; ++kt) {
    const int K0 = kt * 64;
    half8 av[4], bv[4];
#pragma unroll
    for (int q = 0; q < 4; ++q) {
      int s = q * 256 + tid;
      int row = s >> 3, c8 = s & 7;
      av[q] = *(const half8*)(xsk + (size_t)(mt * 128 + row) * 512 + K0 + c8 * 8);
      bv[q] = *(const half8*)(wk  + (size_t)(nt * 128 + row) * 512 + K0 + c8 * 8);
    }
#pragma unroll
    for (int q = 0; q < 4; ++q) {
      int s = q * 256 + tid;
      int row = s >> 3, c8 = s & 7;
      *(half8*)&SL[row * 72 + c8 * 8]        = av[q];
      *(half8*)&SL[9216 + row * 72 + c8 * 8] = bv[q];
    }
    __syncthreads();
#pragma unroll
    for (int ks = 0; ks < 2; ++ks) {
      half8 af[4], bf[4];
#pragma unroll
      for (int fm = 0; fm < 4; ++fm)
        af[fm] = *(const half8*)&SL[(wm * 64 + fm * 16 + lr) * 72 + (ks * 4 + lk) * 8];
#pragma unroll
      for (int fn = 0; fn < 4; ++fn)
        bf[fn] = *(const half8*)&SL[9216 + (wn * 64 + fn * 16 + lr) * 72 + (ks * 4 + lk) * 8];
#pragma unroll
      for (int fm = 0; fm < 4; ++fm)
#pragma unroll
        for (int fn = 0; fn < 4; ++fn)
          acc[fm][fn] = __builtin_amdgcn_mfma_f32_16x16x32_f16(af[fm], bf[fn], acc[fm][fn], 0, 0, 0);
    }
    __syncthreads();
  }
  float bias[4];
#pragma unroll
  for (int fn = 0; fn < 4; ++fn) {
    int g = nt * 128 + wn * 64 + fn * 16 + lr;
    bias[fn] = bih[kb * 1024 + g] + bhh[kb * 1024 + g];
  }
#pragma unroll
  for (int fm = 0; fm < 4; ++fm)
#pragma unroll
    for (int fn = 0; fn < 4; ++fn) {
      int colb = wn * 64 + fn * 16 + lr;
#pragma unroll
      for (int r = 0; r < 4; ++r) {
        int rowb = wm * 64 + fm * 16 + lk * 4 + r;
        SL[rowb * 128 + colb] = (_Float16)(acc[fm][fn][r] + bias[fn]);
      }
    }
  __syncthreads();
#pragma unroll
  for (int q = 0; q < 8; ++q) {
    int s = q * 256 + tid;
    int row = s >> 4, c16 = s & 15;
    int R = mt * 128 + row;
    size_t off = ((size_t)(kb * 64 + (R >> 5)) * 512 + chunk * 32 + (R & 31)) * 1024 + nt * 128 + c16 * 8;
    *(uintx4*)(xg + off) = *(const uintx4*)&SL[row * 128 + c16 * 8];
  }
}

// ---------------- phase 2: ONE launch, 256 blocks x 1024 threads, 512 steps ----------------
// Same byte split as r19 (stream 131 KB/step via gates 0,3; LDS 128 KB via gates 1,2) but at
// 4 waves/SIMD (1024 threads, K-split-4: thread j=tid>>2 owns unit j, lane qt=tid&3 owns
// K-quarter [qt*64,qt*64+64)) -- the occupancy A/B: r19's regression was phase serialization
// at 2 waves/SIMD (L2-wait + LDS-wait + VALU ran in series); 4 waves/SIMD overlaps them.
// Arithmetic identical to r14's refcheck'd kernel (butterfly shfl_xor(1,2), per-lane xg add,
// DS8 first-step scale). Plain __syncthreads loop; slab 8 steps; hist 8 steps.
// LDS dw: [0,128) h8 [2][256] i8 | [128,4224) slab [8][1024] f16 | [4224,5248) hist [8][256] f16
//         | [5248,38016) wl4 [8][1024] quads.  Total 152,064 B.
__global__ __launch_bounds__(1024, 4)
void lstm_all(const _Float16* __restrict__ xg,
              const uintx4* __restrict__ wq8,
              const float* __restrict__ h0,
              const float* __restrict__ c0,
              float* __restrict__ out) {
  extern __shared__ uint32 lds[];
  unsigned char* h8   = (unsigned char*)lds;            // [2][256] i8
  const _Float16* slab = (const _Float16*)(lds + 128);  // [8][1024]
  _Float16*      hist = (_Float16*)(lds + 4224);        // [8][256]
  uintx4*        wl4  = (uintx4*)(lds + 5248);          // [8][1024]
  const int tid = threadIdx.x;
  const int j = tid >> 2, qt = tid & 3;
  const int k = blockIdx.x >> 6, b = blockIdx.x & 63;

  // weight quads: gate g quad i of (j, qt) at wb[i*1024 + g*256 + j], wb = wq8 + (k*4+qt)*4096
  const uintx4* wb = wq8 + ((size_t)(k * 4 + qt) << 12);
  // gates 0,3 -> 8 named quads (compiler streams them per step, pipelined -- r18 pattern)
  uintx4 S0_0 = wb[j],        S0_1 = wb[1024 + j],        S0_2 = wb[2048 + j],        S0_3 = wb[3072 + j];
  uintx4 S3_0 = wb[768 + j],  S3_1 = wb[1024 + 768 + j],  S3_2 = wb[2048 + 768 + j],  S3_3 = wb[3072 + 768 + j];
  // gates 1,2 -> LDS, lane-consecutive: slot (g-1)*4 + i
#pragma unroll
  for (int i = 0; i < 4; ++i) {
    wl4[i * 1024 + tid]       = wb[i * 1024 + 256 + j];
    wl4[(4 + i) * 1024 + tid] = wb[i * 1024 + 512 + j];
  }

  const int gi = b * 1024 + k * 256 + j;
  float cst = c0[gi];
  float hn_prev = h0[gi];
  if (qt == 0) {
    int q = (int)rintf(hn_prev * (127.0f / 8.0f));   // h0 unbounded -> scale 8
    q = q > 127 ? 127 : (q < -127 ? -127 : q);
    h8[j] = (unsigned char)(q & 0xff);
  }

  const float DS1 = 0.0625f / 16129.0f;   // (1/16 / 127) * (1 / 127)
  const float DS8 = 8.0f * DS1;

  const _Float16* xgp = xg + ((size_t)(k * 64 + b) << 19);   // 512 steps * 1024 gates

#define MQ(W, H, d) { d = dot4(W[0], H[0], d); d = dot4(W[1], H[1], d); \
                      d = dot4(W[2], H[2], d); d = dot4(W[3], H[3], d); }
#define STEPI(i) { uintx4 hq = hp4[qt * 4 + (i)]; \
    MQ(S0_##i, hq, d0) \
    { uintx4 w = wl4[(i) * 1024 + tid];       MQ(w, hq, d1) } \
    { uintx4 w = wl4[(4 + (i)) * 1024 + tid]; MQ(w, hq, d2) } \
    MQ(S3_##i, hq, d3) }

#pragma unroll 1
  for (int t = 0; t < 512; ++t) {
    if ((t & 7) == 0) {
      if (t) {  // dump previous 8 steps' h (2048 f16, 2 per thread)
        int tb = t - 8;
#pragma unroll
        for (int q = 0; q < 2; ++q) {
          int idx = q * 1024 + tid;
          int ct = idx >> 8, jj = idx & 255;
          out[((size_t)(tb + ct) * 64 + b) * 1024 + k * 256 + jj] = (float)hist[idx];
        }
      }
      // stage 8 steps of gates: 16 KB = 1024 threads x 16 B, linear global -> linear LDS
      __builtin_amdgcn_global_load_lds(
          (const __attribute__((address_space(1))) void*)(xgp + (size_t)t * 1024 + tid * 8),
          (__attribute__((address_space(3))) void*)(lds + 128 + tid * 4), 16, 0, 0);
      asm volatile("s_waitcnt vmcnt(0)" ::: "memory");
      __syncthreads();
    }

    const uintx4* hp4 = (const uintx4*)(h8 + (t & 1) * 256);
    int d0 = 0, d1 = 0, d2 = 0, d3 = 0;
    STEPI(0) STEPI(1) STEPI(2) STEPI(3)

    float xv = (float)slab[(t & 7) * 1024 + qt * 256 + j];   // lane qt holds gate-qt's xg

    float dsc = (t == 0) ? DS8 : DS1;
    float s0 = (float)d0 * dsc + ((qt == 0) ? xv : 0.0f);
    float s1 = (float)d1 * dsc + ((qt == 1) ? xv : 0.0f);
    float s2 = (float)d2 * dsc + ((qt == 2) ? xv : 0.0f);
    float s3 = (float)d3 * dsc + ((qt == 3) ? xv : 0.0f);
    // butterfly over the 4 qt lanes (adjacent): full gate sums in all lanes
    s0 += __shfl_xor(s0, 1, 64); s0 += __shfl_xor(s0, 2, 64);
    s1 += __shfl_xor(s1, 1, 64); s1 += __shfl_xor(s1, 2, 64);
    s2 += __shfl_xor(s2, 1, 64); s2 += __shfl_xor(s2, 2, 64);
    s3 += __shfl_xor(s3, 1, 64); s3 += __shfl_xor(s3, 2, 64);

    float cn = sigm(s1) * cst + sigm(s0) * tanh_(s2);
    float hn = sigm(s3) * tanh_(cn);
    cst = cn; hn_prev = hn;
    if (qt == 0) {
      hist[(t & 7) * 256 + j] = (_Float16)hn;
      int q = (int)rintf(hn * 127.0f);   // |hn| < 1
      h8[((t & 1) ^ 1) * 256 + j] = (unsigned char)(q & 0xff);
    }
    __syncthreads();
  }
#undef MQ
#undef STEPI

  // dump last 8 steps
#pragma unroll
  for (int q = 0; q < 2; ++q) {
    int idx = q * 1024 + tid;
    int ct = idx >> 8, jj = idx & 255;
    out[((size_t)(504 + ct) * 64 + b) * 1024 + k * 256 + jj] = (float)hist[idx];
  }
  if (qt == 0) out[33554432 + gi] = hn_prev;           // new_h
  if (qt == 1) out[33554432 + 65536 + gi] = cst;       // new_c
}

extern "C" void kernel_launch(void* const* d_in, const int* in_sizes, int n_in,
                              void* d_out, int out_size, void* d_ws, size_t ws_size,
                              hipStream_t stream) {
  const float* x   = (const float*)d_in[0];
  const float* h0  = (const float*)d_in[1];
  const float* c0  = (const float*)d_in[2];
  const float* Wih = (const float*)d_in[3];
  const float* Whh = (const float*)d_in[4];
  const float* bih = (const float*)d_in[5];
  const float* bhh = (const float*)d_in[6];
  float* out = (float*)d_out;
  char* ws = (char*)d_ws;

  // ws usage: 407,896,064 B (r14 fills showed ws >= ~514 MB)
  _Float16* xg16  = (_Float16*)ws;                   // 268,435,456 B  [k][b][t 512][gate]
  _Float16* xs    = (_Float16*)(ws + 268435456L);    // 134,217,728 B  [chunk][k][R][512]
  _Float16* wih16 = (_Float16*)(ws + 402653184L);    //   4,194,304 B
  uintx4*   wq8   = (uintx4*)(ws + 406847488L);      //   1,048,576 B  (i8 weights)

  hipFuncSetAttribute((const void*)lstm_all, hipFuncAttributeMaxDynamicSharedMemorySize, 152064);

  pack_wih<<<4096, 256, 0, stream>>>(Wih, (uint32*)wih16);
  pack_whh8<<<256, 256, 0, stream>>>(Whh, wq8);
  pack_x_all<<<8192, 256, 0, stream>>>(x, (uint32*)xs);
  gemm_all<<<8192, 256, 0, stream>>>(xs, wih16, bih, bhh, xg16);
  lstm_all<<<256, 1024, 152064, stream>>>(xg16, wq8, h0, c0, out);
}

// Round 21
// 967.114 us; speedup vs baseline: 1.2402x; 1.2402x over previous
//
#include <hip/hip_runtime.h>

typedef _Float16 half8   __attribute__((ext_vector_type(8)));
typedef _Float16 half2_t __attribute__((ext_vector_type(2)));
typedef float    floatx4 __attribute__((ext_vector_type(4)));
typedef unsigned int uintx4 __attribute__((ext_vector_type(4)));
typedef unsigned int uint32;

__device__ __forceinline__ float sigm(float v) { return 1.0f / (1.0f + __expf(-v)); }
__device__ __forceinline__ float tanh_(float v) { float e = __expf(2.0f * v); return (e - 1.0f) / (e + 1.0f); }

__device__ __forceinline__ int dot4(uint32 a, uint32 b, int c) {
#if __has_builtin(__builtin_amdgcn_sdot4)
  return __builtin_amdgcn_sdot4((int)a, (int)b, c, false);
#else
  int r = c;
  r += (int)(char)(a)       * (int)(char)(b);
  r += (int)(char)(a >> 8)  * (int)(char)(b >> 8);
  r += (int)(char)(a >> 16) * (int)(char)(b >> 16);
  r += (int)(char)(a >> 24) * (int)(char)(b >> 24);
  return r;
#endif
}

__device__ __forceinline__ uint32 pack_rte(float a, float b) {
  half2_t h; h[0] = (_Float16)a; h[1] = (_Float16)b;
  return __builtin_bit_cast(uint32, h);
}

// ---------------- pack W_ih: f32 -> f16 pairs, flat ----------------
__global__ __launch_bounds__(256) void pack_wih(const float* __restrict__ wih, uint32* __restrict__ wihd) {
  int p = blockIdx.x * 256 + threadIdx.x;   // 1048576 pairs
  wihd[p] = pack_rte(wih[2 * p], wih[2 * p + 1]);
}

// ---------------- pack W_hh: f32 -> i8, layout [k][qt][qi][row], scale 2032 ----------------
__global__ __launch_bounds__(256) void pack_whh8(const float* __restrict__ whh, uintx4* __restrict__ wq8) {
  int p = blockIdx.x * 256 + threadIdx.x;   // 65536 quads
  int row = p & 1023, qi = (p >> 10) & 3, qt = (p >> 12) & 3, kk = p >> 14;
  const float* src = whh + ((size_t)(kk * 1024 + row)) * 256 + qt * 64 + qi * 16;
  uint32 dw[4];
#pragma unroll
  for (int d = 0; d < 4; ++d) {
    uint32 v = 0;
#pragma unroll
    for (int e = 0; e < 4; ++e) {
      int q = (int)rintf(src[d * 4 + e] * 2032.0f);
      q = q > 127 ? 127 : (q < -127 ? -127 : q);
      v |= ((uint32)(q & 0xff)) << (8 * e);
    }
    dw[d] = v;
  }
  wq8[p] = (uintx4){dw[0], dw[1], dw[2], dw[3]};
}

// ---------------- pack ALL x slices: xs[chunk][k][R=b*32+ct][512] f16 ----------------
__global__ __launch_bounds__(256) void pack_x_all(const float* __restrict__ x, uint32* __restrict__ xsd) {
  for (long p = (long)blockIdx.x * 256 + threadIdx.x; p < 33554432L; p += 2097152L) {
    int chunk = (int)(p >> 21);
    int r = (int)(p & 2097151);
    int k  = r >> 19;
    int R  = (r >> 8) & 2047;   // R = b*32 + ct
    int pc = r & 255;
    int b = R >> 5, ct = R & 31;
    int t = chunk * 32 + ct;
    int sk = (k * 1024) / 6;    // 0,170,341,512
    const float* src = x + ((size_t)t * 64 + b) * 1024 + sk + pc * 2;
    xsd[p] = pack_rte(src[0], src[1]);
  }
}

// ---------------- phase 1 (ALL chunks): xg16 = xs @ Wih^T + bias via f16 MFMA ----------------
__global__ __launch_bounds__(256) void gemm_all(const _Float16* __restrict__ xs,
                                                const _Float16* __restrict__ wih16,
                                                const float* __restrict__ bih,
                                                const float* __restrict__ bhh,
                                                _Float16* __restrict__ xg) {
  __shared__ _Float16 SL[18432];
  const int tid = threadIdx.x;
  const int bid = blockIdx.x;
  const int chunk = bid >> 9;
  const int b9 = bid & 511;
  const int nt = b9 & 7, mt = (b9 >> 3) & 15, kb = b9 >> 7;
  const int l = tid & 63;
  const int wid = tid >> 6;
  const int wm = wid >> 1, wn = wid & 1;
  const int lr = l & 15, lk = l >> 4;

  floatx4 acc[4][4] = {};
  const _Float16* xsk = xs + ((size_t)(chunk * 4 + kb) << 20);
  const _Float16* wk  = wih16 + ((size_t)kb << 19);

  for (int kt = 0; kt < 8; ++kt) {
    const int K0 = kt * 64;
    half8 av[4], bv[4];
#pragma unroll
    for (int q = 0; q < 4; ++q) {
      int s = q * 256 + tid;
      int row = s >> 3, c8 = s & 7;
      av[q] = *(const half8*)(xsk + (size_t)(mt * 128 + row) * 512 + K0 + c8 * 8);
      bv[q] = *(const half8*)(wk  + (size_t)(nt * 128 + row) * 512 + K0 + c8 * 8);
    }
#pragma unroll
    for (int q = 0; q < 4; ++q) {
      int s = q * 256 + tid;
      int row = s >> 3, c8 = s & 7;
      *(half8*)&SL[row * 72 + c8 * 8]        = av[q];
      *(half8*)&SL[9216 + row * 72 + c8 * 8] = bv[q];
    }
    __syncthreads();
#pragma unroll
    for (int ks = 0; ks < 2; ++ks) {
      half8 af[4], bf[4];
#pragma unroll
      for (int fm = 0; fm < 4; ++fm)
        af[fm] = *(const half8*)&SL[(wm * 64 + fm * 16 + lr) * 72 + (ks * 4 + lk) * 8];
#pragma unroll
      for (int fn = 0; fn < 4; ++fn)
        bf[fn] = *(const half8*)&SL[9216 + (wn * 64 + fn * 16 + lr) * 72 + (ks * 4 + lk) * 8];
#pragma unroll
      for (int fm = 0; fm < 4; ++fm)
#pragma unroll
        for (int fn = 0; fn < 4; ++fn)
          acc[fm][fn] = __builtin_amdgcn_mfma_f32_16x16x32_f16(af[fm], bf[fn], acc[fm][fn], 0, 0, 0);
    }
    __syncthreads();
  }
  float bias[4];
#pragma unroll
  for (int fn = 0; fn < 4; ++fn) {
    int g = nt * 128 + wn * 64 + fn * 16 + lr;
    bias[fn] = bih[kb * 1024 + g] + bhh[kb * 1024 + g];
  }
#pragma unroll
  for (int fm = 0; fm < 4; ++fm)
#pragma unroll
    for (int fn = 0; fn < 4; ++fn) {
      int colb = wn * 64 + fn * 16 + lr;
#pragma unroll
      for (int r = 0; r < 4; ++r) {
        int rowb = wm * 64 + fm * 16 + lk * 4 + r;
        SL[rowb * 128 + colb] = (_Float16)(acc[fm][fn][r] + bias[fn]);
      }
    }
  __syncthreads();
#pragma unroll
  for (int q = 0; q < 8; ++q) {
    int s = q * 256 + tid;
    int row = s >> 4, c16 = s & 15;
    int R = mt * 128 + row;
    size_t off = ((size_t)(kb * 64 + (R >> 5)) * 512 + chunk * 32 + (R & 31)) * 1024 + nt * 128 + c16 * 8;
    *(uintx4*)(xg + off) = *(const uintx4*)&SL[row * 128 + c16 * 8];
  }
}

// ---------------- phase 2: ONE launch, 256 blocks x 512 threads, 512 steps ----------------
// r18 structure (K-split-2, 2 waves/SIMD, plain __syncthreads loop, 696us winner) with the
// weight split interpolated 24/8 -> 20/12: stream gates 0,1 + gate2 quads 0-3 (20 quads,
// 163 KB/step ~2730cy vs r18's 196 KB = 3270cy which WAS the step time); LDS holds gate2
// quads 4-7 + gate3 (12 quads, 98 KB, lane-consecutive conflict-free). LDS/step ~180 KB
// ~2120cy, VALU ~2120cy -- if r18's overlap quality holds, step ~= stream ~2850-3100cy.
// Pre-committed: lstm >= 700us => r18's 24/8 is the local optimum (revert + roofline).
// LDS dw: [0,128) h8 [2][256] i8 | [128,4224) slab [8][1024] f16 | [4224,5248) hist [8][256] f16
//         | [5248,29824) wl4 [12][512] quads.  Total 119,296 B.
__global__ __launch_bounds__(512, 2)
void lstm_all(const _Float16* __restrict__ xg,
              const uintx4* __restrict__ wq8,
              const float* __restrict__ h0,
              const float* __restrict__ c0,
              float* __restrict__ out) {
  extern __shared__ uint32 lds[];
  unsigned char* h8   = (unsigned char*)lds;            // [2][256] i8
  const _Float16* slab = (const _Float16*)(lds + 128);  // [8][1024]
  _Float16*      hist = (_Float16*)(lds + 4224);        // [8][256]
  uintx4*        wl4  = (uintx4*)(lds + 5248);          // [12][512]
  const int tid = threadIdx.x;
  const int j = tid >> 1, s = tid & 1;
  const int k = blockIdx.x >> 6, b = blockIdx.x & 63;

  const uintx4* wk = wq8 + ((size_t)k << 14);
  // streamed: gates 0,1 (8 quads each) + gate 2 quads 0-3 (compiler pipelines the reloads)
#define LQ(g, i) uintx4 S##g##_##i = wk[(2 * s + ((i) >> 2)) * 4096 + ((i) & 3) * 1024 + (g) * 256 + j];
  LQ(0,0) LQ(0,1) LQ(0,2) LQ(0,3) LQ(0,4) LQ(0,5) LQ(0,6) LQ(0,7)
  LQ(1,0) LQ(1,1) LQ(1,2) LQ(1,3) LQ(1,4) LQ(1,5) LQ(1,6) LQ(1,7)
  LQ(2,0) LQ(2,1) LQ(2,2) LQ(2,3)
#undef LQ
  // LDS: gate 2 quads 4-7 -> slots 0-3; gate 3 quads 0-7 -> slots 4-11 (lane-consecutive)
#pragma unroll
  for (int i = 4; i < 8; ++i)
    wl4[(i - 4) * 512 + tid] = wk[(2 * s + (i >> 2)) * 4096 + (i & 3) * 1024 + 512 + j];
#pragma unroll
  for (int i = 0; i < 8; ++i)
    wl4[(4 + i) * 512 + tid] = wk[(2 * s + (i >> 2)) * 4096 + (i & 3) * 1024 + 768 + j];

  const int gi = b * 1024 + k * 256 + j;
  float cst = c0[gi];
  float hn_prev = h0[gi];
  if (!s) {
    int q = (int)rintf(hn_prev * (127.0f / 8.0f));   // h0 unbounded -> scale 8
    q = q > 127 ? 127 : (q < -127 ? -127 : q);
    h8[j] = (unsigned char)(q & 0xff);
  }

  const float DS1 = 0.0625f / 16129.0f;   // (1/16 / 127) * (1 / 127)
  const float DS8 = 8.0f * DS1;

  const _Float16* xgp = xg + ((size_t)(k * 64 + b) << 19);   // 512 steps * 1024 gates

#define MQ(W, H, d) { d = dot4(W[0], H[0], d); d = dot4(W[1], H[1], d); \
                      d = dot4(W[2], H[2], d); d = dot4(W[3], H[3], d); }
#define STEPA(i) { uintx4 hq = hp4[s * 8 + (i)]; \
    MQ(S0_##i, hq, d0) MQ(S1_##i, hq, d1) MQ(S2_##i, hq, d2) \
    { uintx4 w = wl4[(4 + (i)) * 512 + tid]; MQ(w, hq, d3) } }
#define STEPB(i) { uintx4 hq = hp4[s * 8 + (i)]; \
    MQ(S0_##i, hq, d0) MQ(S1_##i, hq, d1) \
    { uintx4 w = wl4[((i) - 4) * 512 + tid]; MQ(w, hq, d2) } \
    { uintx4 w = wl4[(4 + (i)) * 512 + tid]; MQ(w, hq, d3) } }

#pragma unroll 1
  for (int t = 0; t < 512; ++t) {
    if ((t & 7) == 0) {
      if (t) {  // dump previous 8 steps' h (2048 f16, 4 per thread)
        int tb = t - 8;
#pragma unroll
        for (int q = 0; q < 4; ++q) {
          int idx = q * 512 + tid;
          int ct = idx >> 8, jj = idx & 255;
          out[((size_t)(tb + ct) * 64 + b) * 1024 + k * 256 + jj] = (float)hist[idx];
        }
      }
      // stage 8 steps of gates: 16 KB, linear global -> linear LDS
#pragma unroll
      for (int q = 0; q < 2; ++q)
        __builtin_amdgcn_global_load_lds(
            (const __attribute__((address_space(1))) void*)(xgp + (size_t)t * 1024 + q * 4096 + tid * 8),
            (__attribute__((address_space(3))) void*)(lds + 128 + q * 2048 + tid * 4), 16, 0, 0);
      asm volatile("s_waitcnt vmcnt(0)" ::: "memory");
      __syncthreads();
    }

    const uintx4* hp4 = (const uintx4*)(h8 + (t & 1) * 256);
    int d0 = 0, d1 = 0, d2 = 0, d3 = 0;
    STEPA(0) STEPA(1) STEPA(2) STEPA(3) STEPB(4) STEPB(5) STEPB(6) STEPB(7)

    // sum the two K-halves across the lane pair (both lanes end with full sums)
    d0 += __shfl_xor(d0, 1, 64);
    d1 += __shfl_xor(d1, 1, 64);
    d2 += __shfl_xor(d2, 1, 64);
    d3 += __shfl_xor(d3, 1, 64);

    const int ts = (t & 7) * 1024;
    float xi = (float)slab[ts + j];
    float xf = (float)slab[ts + 256 + j];
    float xgv = (float)slab[ts + 512 + j];
    float xo = (float)slab[ts + 768 + j];

    float dsc = (t == 0) ? DS8 : DS1;
    float iv = (float)d0 * dsc + xi;
    float fv = (float)d1 * dsc + xf;
    float gv = (float)d2 * dsc + xgv;
    float ov = (float)d3 * dsc + xo;
    float cn = sigm(fv) * cst + sigm(iv) * tanh_(gv);
    float hn = sigm(ov) * tanh_(cn);
    cst = cn; hn_prev = hn;
    if (!s) {
      hist[(t & 7) * 256 + j] = (_Float16)hn;
      int q = (int)rintf(hn * 127.0f);   // |hn| < 1
      h8[((t & 1) ^ 1) * 256 + j] = (unsigned char)(q & 0xff);
    }
    __syncthreads();
  }
#undef MQ
#undef STEPA
#undef STEPB

  // dump last 8 steps
#pragma unroll
  for (int q = 0; q < 4; ++q) {
    int idx = q * 512 + tid;
    int ct = idx >> 8, jj = idx & 255;
    out[((size_t)(504 + ct) * 64 + b) * 1024 + k * 256 + jj] = (float)hist[idx];
  }
  if (!s) {
    out[33554432 + gi] = hn_prev;          // new_h
    out[33554432 + 65536 + gi] = cst;      // new_c
  }
}

extern "C" void kernel_launch(void* const* d_in, const int* in_sizes, int n_in,
                              void* d_out, int out_size, void* d_ws, size_t ws_size,
                              hipStream_t stream) {
  const float* x   = (const float*)d_in[0];
  const float* h0  = (const float*)d_in[1];
  const float* c0  = (const float*)d_in[2];
  const float* Wih = (const float*)d_in[3];
  const float* Whh = (const float*)d_in[4];
  const float* bih = (const float*)d_in[5];
  const float* bhh = (const float*)d_in[6];
  float* out = (float*)d_out;
  char* ws = (char*)d_ws;

  // ws usage: 407,896,064 B (r14 fills showed ws >= ~514 MB)
  _Float16* xg16  = (_Float16*)ws;                   // 268,435,456 B  [k][b][t 512][gate]
  _Float16* xs    = (_Float16*)(ws + 268435456L);    // 134,217,728 B  [chunk][k][R][512]
  _Float16* wih16 = (_Float16*)(ws + 402653184L);    //   4,194,304 B
  uintx4*   wq8   = (uintx4*)(ws + 406847488L);      //   1,048,576 B  (i8 weights)

  hipFuncSetAttribute((const void*)lstm_all, hipFuncAttributeMaxDynamicSharedMemorySize, 119296);

  pack_wih<<<4096, 256, 0, stream>>>(Wih, (uint32*)wih16);
  pack_whh8<<<256, 256, 0, stream>>>(Whh, wq8);
  pack_x_all<<<8192, 256, 0, stream>>>(x, (uint32*)xs);
  gemm_all<<<8192, 256, 0, stream>>>(xs, wih16, bih, bhh, xg16);
  lstm_all<<<256, 512, 119296, stream>>>(xg16, wq8, h0, c0, out);
}

// Round 22
// 957.687 us; speedup vs baseline: 1.2524x; 1.0098x over previous
//
#include <hip/hip_runtime.h>

typedef _Float16 half8   __attribute__((ext_vector_type(8)));
typedef _Float16 half2_t __attribute__((ext_vector_type(2)));
typedef float    floatx4 __attribute__((ext_vector_type(4)));
typedef unsigned int uintx4 __attribute__((ext_vector_type(4)));
typedef unsigned int uint32;

__device__ __forceinline__ float sigm(float v) { return 1.0f / (1.0f + __expf(-v)); }
__device__ __forceinline__ float tanh_(float v) { float e = __expf(2.0f * v); return (e - 1.0f) / (e + 1.0f); }

__device__ __forceinline__ int dot4(uint32 a, uint32 b, int c) {
#if __has_builtin(__builtin_amdgcn_sdot4)
  return __builtin_amdgcn_sdot4((int)a, (int)b, c, false);
#else
  int r = c;
  r += (int)(char)(a)       * (int)(char)(b);
  r += (int)(char)(a >> 8)  * (int)(char)(b >> 8);
  r += (int)(char)(a >> 16) * (int)(char)(b >> 16);
  r += (int)(char)(a >> 24) * (int)(char)(b >> 24);
  return r;
#endif
}

__device__ __forceinline__ uint32 pack_rte(float a, float b) {
  half2_t h; h[0] = (_Float16)a; h[1] = (_Float16)b;
  return __builtin_bit_cast(uint32, h);
}

// ---------------- pack W_ih: f32 -> f16 pairs, flat ----------------
__global__ __launch_bounds__(256) void pack_wih(const float* __restrict__ wih, uint32* __restrict__ wihd) {
  int p = blockIdx.x * 256 + threadIdx.x;   // 1048576 pairs
  wihd[p] = pack_rte(wih[2 * p], wih[2 * p + 1]);
}

// ---------------- pack W_hh: f32 -> i8, layout [k][qt][qi][row], scale 2032 ----------------
__global__ __launch_bounds__(256) void pack_whh8(const float* __restrict__ whh, uintx4* __restrict__ wq8) {
  int p = blockIdx.x * 256 + threadIdx.x;   // 65536 quads
  int row = p & 1023, qi = (p >> 10) & 3, qt = (p >> 12) & 3, kk = p >> 14;
  const float* src = whh + ((size_t)(kk * 1024 + row)) * 256 + qt * 64 + qi * 16;
  uint32 dw[4];
#pragma unroll
  for (int d = 0; d < 4; ++d) {
    uint32 v = 0;
#pragma unroll
    for (int e = 0; e < 4; ++e) {
      int q = (int)rintf(src[d * 4 + e] * 2032.0f);
      q = q > 127 ? 127 : (q < -127 ? -127 : q);
      v |= ((uint32)(q & 0xff)) << (8 * e);
    }
    dw[d] = v;
  }
  wq8[p] = (uintx4){dw[0], dw[1], dw[2], dw[3]};
}

// ---------------- pack ALL x slices: xs[chunk][k][R=b*32+ct][512] f16 ----------------
__global__ __launch_bounds__(256) void pack_x_all(const float* __restrict__ x, uint32* __restrict__ xsd) {
  for (long p = (long)blockIdx.x * 256 + threadIdx.x; p < 33554432L; p += 2097152L) {
    int chunk = (int)(p >> 21);
    int r = (int)(p & 2097151);
    int k  = r >> 19;
    int R  = (r >> 8) & 2047;   // R = b*32 + ct
    int pc = r & 255;
    int b = R >> 5, ct = R & 31;
    int t = chunk * 32 + ct;
    int sk = (k * 1024) / 6;    // 0,170,341,512
    const float* src = x + ((size_t)t * 64 + b) * 1024 + sk + pc * 2;
    xsd[p] = pack_rte(src[0], src[1]);
  }
}

// ---------------- phase 1 (ALL chunks): xg16 = xs @ Wih^T + bias via f16 MFMA ----------------
__global__ __launch_bounds__(256) void gemm_all(const _Float16* __restrict__ xs,
                                                const _Float16* __restrict__ wih16,
                                                const float* __restrict__ bih,
                                                const float* __restrict__ bhh,
                                                _Float16* __restrict__ xg) {
  __shared__ _Float16 SL[18432];
  const int tid = threadIdx.x;
  const int bid = blockIdx.x;
  const int chunk = bid >> 9;
  const int b9 = bid & 511;
  const int nt = b9 & 7, mt = (b9 >> 3) & 15, kb = b9 >> 7;
  const int l = tid & 63;
  const int wid = tid >> 6;
  const int wm = wid >> 1, wn = wid & 1;
  const int lr = l & 15, lk = l >> 4;

  floatx4 acc[4][4] = {};
  const _Float16* xsk = xs + ((size_t)(chunk * 4 + kb) << 20);
  const _Float16* wk  = wih16 + ((size_t)kb << 19);

  for (int kt = 0; kt < 8; ++kt) {
    const int K0 = kt * 64;
    half8 av[4], bv[4];
#pragma unroll
    for (int q = 0; q < 4; ++q) {
      int s = q * 256 + tid;
      int row = s >> 3, c8 = s & 7;
      av[q] = *(const half8*)(xsk + (size_t)(mt * 128 + row) * 512 + K0 + c8 * 8);
      bv[q] = *(const half8*)(wk  + (size_t)(nt * 128 + row) * 512 + K0 + c8 * 8);
    }
#pragma unroll
    for (int q = 0; q < 4; ++q) {
      int s = q * 256 + tid;
      int row = s >> 3, c8 = s & 7;
      *(half8*)&SL[row * 72 + c8 * 8]        = av[q];
      *(half8*)&SL[9216 + row * 72 + c8 * 8] = bv[q];
    }
    __syncthreads();
#pragma unroll
    for (int ks = 0; ks < 2; ++ks) {
      half8 af[4], bf[4];
#pragma unroll
      for (int fm = 0; fm < 4; ++fm)
        af[fm] = *(const half8*)&SL[(wm * 64 + fm * 16 + lr) * 72 + (ks * 4 + lk) * 8];
#pragma unroll
      for (int fn = 0; fn < 4; ++fn)
        bf[fn] = *(const half8*)&SL[9216 + (wn * 64 + fn * 16 + lr) * 72 + (ks * 4 + lk) * 8];
#pragma unroll
      for (int fm = 0; fm < 4; ++fm)
#pragma unroll
        for (int fn = 0; fn < 4; ++fn)
          acc[fm][fn] = __builtin_amdgcn_mfma_f32_16x16x32_f16(af[fm], bf[fn], acc[fm][fn], 0, 0, 0);
    }
    __syncthreads();
  }
  float bias[4];
#pragma unroll
  for (int fn = 0; fn < 4; ++fn) {
    int g = nt * 128 + wn * 64 + fn * 16 + lr;
    bias[fn] = bih[kb * 1024 + g] + bhh[kb * 1024 + g];
  }
#pragma unroll
  for (int fm = 0; fm < 4; ++fm)
#pragma unroll
    for (int fn = 0; fn < 4; ++fn) {
      int colb = wn * 64 + fn * 16 + lr;
#pragma unroll
      for (int r = 0; r < 4; ++r) {
        int rowb = wm * 64 + fm * 16 + lk * 4 + r;
        SL[rowb * 128 + colb] = (_Float16)(acc[fm][fn][r] + bias[fn]);
      }
    }
  __syncthreads();
#pragma unroll
  for (int q = 0; q < 8; ++q) {
    int s = q * 256 + tid;
    int row = s >> 4, c16 = s & 15;
    int R = mt * 128 + row;
    size_t off = ((size_t)(kb * 64 + (R >> 5)) * 512 + chunk * 32 + (R & 31)) * 1024 + nt * 128 + c16 * 8;
    *(uintx4*)(xg + off) = *(const uintx4*)&SL[row * 128 + c16 * 8];
  }
}

// ---------------- phase 2: ONE launch, 256 blocks x 512 threads, 512 steps ----------------
// r18 VERBATIM (best: lstm 696us, step == L2 stream time exactly). K-split-2, 2 waves/SIMD,
// plain __syncthreads loop. Weight split 24 streamed / 8 LDS -- the empirical optimum of the
// r15-r21 sweep (32/0=922, 24/8=696, 20/12=712, 16/16=766, 8/16@4w=970): streaming 196 KB/step
// saturates the per-CU L2 share (60 B/cy) while LDS+VALU hide fully beneath it; any further
// LDS shift exposes the LDS pipe by more than the stream saves.
// LDS dw: [0,128) h8 [2][256] i8 | [128,4224) slab [8][1024] f16 | [4224,5248) hist [8][256] f16
//         | [5248,21632) wl4 [8][512] quads.  Total 86,528 B.
__global__ __launch_bounds__(512, 2)
void lstm_all(const _Float16* __restrict__ xg,
              const uintx4* __restrict__ wq8,
              const float* __restrict__ h0,
              const float* __restrict__ c0,
              float* __restrict__ out) {
  extern __shared__ uint32 lds[];
  unsigned char* h8   = (unsigned char*)lds;            // [2][256] i8
  const _Float16* slab = (const _Float16*)(lds + 128);  // [8][1024]
  _Float16*      hist = (_Float16*)(lds + 4224);        // [8][256]
  uintx4*        wl4  = (uintx4*)(lds + 5248);          // [8][512]
  const int tid = threadIdx.x;
  const int j = tid >> 1, s = tid & 1;
  const int k = blockIdx.x >> 6, b = blockIdx.x & 63;

  const uintx4* wk = wq8 + ((size_t)k << 14);
  // gates 0,1,2 K-half s: 24 named quads (compiler streams them per step, pipelined)
#define LQ(g, i) uintx4 S##g##_##i = wk[(2 * s + ((i) >> 2)) * 4096 + ((i) & 3) * 1024 + (g) * 256 + j];
  LQ(0,0) LQ(0,1) LQ(0,2) LQ(0,3) LQ(0,4) LQ(0,5) LQ(0,6) LQ(0,7)
  LQ(1,0) LQ(1,1) LQ(1,2) LQ(1,3) LQ(1,4) LQ(1,5) LQ(1,6) LQ(1,7)
  LQ(2,0) LQ(2,1) LQ(2,2) LQ(2,3) LQ(2,4) LQ(2,5) LQ(2,6) LQ(2,7)
#undef LQ
  // gate 3 K-half s -> LDS, lane-consecutive
#pragma unroll
  for (int i = 0; i < 8; ++i)
    wl4[i * 512 + tid] = wk[(2 * s + (i >> 2)) * 4096 + (i & 3) * 1024 + 768 + j];

  const int gi = b * 1024 + k * 256 + j;
  float cst = c0[gi];
  float hn_prev = h0[gi];
  if (!s) {
    int q = (int)rintf(hn_prev * (127.0f / 8.0f));   // h0 unbounded -> scale 8
    q = q > 127 ? 127 : (q < -127 ? -127 : q);
    h8[j] = (unsigned char)(q & 0xff);
  }

  const float DS1 = 0.0625f / 16129.0f;   // (1/16 / 127) * (1 / 127)
  const float DS8 = 8.0f * DS1;

  const _Float16* xgp = xg + ((size_t)(k * 64 + b) << 19);   // 512 steps * 1024 gates

#define MQ(W, H, d) { d = dot4(W[0], H[0], d); d = dot4(W[1], H[1], d); \
                      d = dot4(W[2], H[2], d); d = dot4(W[3], H[3], d); }
#define STEPI(i) { uintx4 hq = hp4[s * 8 + (i)]; \
    MQ(S0_##i, hq, d0) MQ(S1_##i, hq, d1) MQ(S2_##i, hq, d2) \
    { uintx4 w = wl4[(i) * 512 + tid]; MQ(w, hq, d3) } }

#pragma unroll 1
  for (int t = 0; t < 512; ++t) {
    if ((t & 7) == 0) {
      if (t) {  // dump previous 8 steps' h (2048 f16, 4 per thread)
        int tb = t - 8;
#pragma unroll
        for (int q = 0; q < 4; ++q) {
          int idx = q * 512 + tid;
          int ct = idx >> 8, jj = idx & 255;
          out[((size_t)(tb + ct) * 64 + b) * 1024 + k * 256 + jj] = (float)hist[idx];
        }
      }
      // stage 8 steps of gates: 16 KB, linear global -> linear LDS
#pragma unroll
      for (int q = 0; q < 2; ++q)
        __builtin_amdgcn_global_load_lds(
            (const __attribute__((address_space(1))) void*)(xgp + (size_t)t * 1024 + q * 4096 + tid * 8),
            (__attribute__((address_space(3))) void*)(lds + 128 + q * 2048 + tid * 4), 16, 0, 0);
      asm volatile("s_waitcnt vmcnt(0)" ::: "memory");
      __syncthreads();
    }

    const uintx4* hp4 = (const uintx4*)(h8 + (t & 1) * 256);
    int d0 = 0, d1 = 0, d2 = 0, d3 = 0;
    STEPI(0) STEPI(1) STEPI(2) STEPI(3) STEPI(4) STEPI(5) STEPI(6) STEPI(7)

    // sum the two K-halves across the lane pair (both lanes end with full sums)
    d0 += __shfl_xor(d0, 1, 64);
    d1 += __shfl_xor(d1, 1, 64);
    d2 += __shfl_xor(d2, 1, 64);
    d3 += __shfl_xor(d3, 1, 64);

    const int ts = (t & 7) * 1024;
    float xi = (float)slab[ts + j];
    float xf = (float)slab[ts + 256 + j];
    float xgv = (float)slab[ts + 512 + j];
    float xo = (float)slab[ts + 768 + j];

    float dsc = (t == 0) ? DS8 : DS1;
    float iv = (float)d0 * dsc + xi;
    float fv = (float)d1 * dsc + xf;
    float gv = (float)d2 * dsc + xgv;
    float ov = (float)d3 * dsc + xo;
    float cn = sigm(fv) * cst + sigm(iv) * tanh_(gv);
    float hn = sigm(ov) * tanh_(cn);
    cst = cn; hn_prev = hn;
    if (!s) {
      hist[(t & 7) * 256 + j] = (_Float16)hn;
      int q = (int)rintf(hn * 127.0f);   // |hn| < 1
      h8[((t & 1) ^ 1) * 256 + j] = (unsigned char)(q & 0xff);
    }
    __syncthreads();
  }
#undef MQ
#undef STEPI

  // dump last 8 steps
#pragma unroll
  for (int q = 0; q < 4; ++q) {
    int idx = q * 512 + tid;
    int ct = idx >> 8, jj = idx & 255;
    out[((size_t)(504 + ct) * 64 + b) * 1024 + k * 256 + jj] = (float)hist[idx];
  }
  if (!s) {
    out[33554432 + gi] = hn_prev;          // new_h
    out[33554432 + 65536 + gi] = cst;      // new_c
  }
}

extern "C" void kernel_launch(void* const* d_in, const int* in_sizes, int n_in,
                              void* d_out, int out_size, void* d_ws, size_t ws_size,
                              hipStream_t stream) {
  const float* x   = (const float*)d_in[0];
  const float* h0  = (const float*)d_in[1];
  const float* c0  = (const float*)d_in[2];
  const float* Wih = (const float*)d_in[3];
  const float* Whh = (const float*)d_in[4];
  const float* bih = (const float*)d_in[5];
  const float* bhh = (const float*)d_in[6];
  float* out = (float*)d_out;
  char* ws = (char*)d_ws;

  // ws usage: 407,896,064 B (r14 fills showed ws >= ~514 MB)
  _Float16* xg16  = (_Float16*)ws;                   // 268,435,456 B  [k][b][t 512][gate]
  _Float16* xs    = (_Float16*)(ws + 268435456L);    // 134,217,728 B  [chunk][k][R][512]
  _Float16* wih16 = (_Float16*)(ws + 402653184L);    //   4,194,304 B
  uintx4*   wq8   = (uintx4*)(ws + 406847488L);      //   1,048,576 B  (i8 weights)

  hipFuncSetAttribute((const void*)lstm_all, hipFuncAttributeMaxDynamicSharedMemorySize, 86528);

  pack_wih<<<4096, 256, 0, stream>>>(Wih, (uint32*)wih16);
  pack_whh8<<<256, 256, 0, stream>>>(Whh, wq8);
  pack_x_all<<<8192, 256, 0, stream>>>(x, (uint32*)xs);
  gemm_all<<<8192, 256, 0, stream>>>(xs, wih16, bih, bhh, xg16);
  lstm_all<<<256, 512, 86528, stream>>>(xg16, wq8, h0, c0, out);
}